// Round 1
// baseline (13974.318 us; speedup 1.0000x reference)
//
#include <hip/hip_runtime.h>
#include <hip/hip_fp16.h>

#define HDIM 256
#define LSEQ 512
#define PRED 96
#define NB 16   // batch columns per block
#define NBLK (256 / NB)

typedef _Float16 f16x8 __attribute__((ext_vector_type(8)));
typedef _Float16 f16x4 __attribute__((ext_vector_type(4)));
typedef float f32x4 __attribute__((ext_vector_type(4)));

__device__ __forceinline__ float sigm(float x) { return 1.f / (1.f + __expf(-x)); }
__device__ __forceinline__ float tanh_(float x) { float t = __expf(2.f * x); return 1.f - 2.f / (t + 1.f); }

// LDS: h state double-buffered, split f16 hi/lo (hi+lo == f32 h to ~2^-22).
// Row layout [n][256+8pad]: B-frag ds_read_b128 at n*528 + kt*64 + q*16 bytes
// -> 16B-group = (33n + q) mod 8: all 8 bank-groups hit evenly, conflict-free.
struct __align__(16) RecSmem {
  _Float16 h[2][2][NB][264];  // [buf][hi/lo][col n][256+8]  : 33792 B
  float xt[LSEQ][NB];         // kernel-1 staged input slice : 32768 B
  float red[8][NB];
  float inp[NB];
};

// park a f16x8 in AGPRs (tied-operand class cast; copy happens once, pre-loop)
#define CAST_A(DST, SRC) asm("" : "=a"(DST) : "0"(SRC))

#define ROFF(G, S) (256 * (G) + 32 * w + 16 * (S) + 4 * q)

#define DECL_MM                                                                \
  f16x8 A[6][8];   /* this wave's 6 A-tiles x 8 k-frags -> 192 AGPRs */        \
  f32x4 biasC[6];  /* folded into MFMA C operand of kt=0 */                    \
  f16x8 bh[8], bl[8];                                                          \
  f32x4 ac[6];                                                                 \
  float hold[2][4]; /* h_old for this lane's 8 rows, f32, register-resident */

// A-frag (m89/m91-verified layout, same as proven gemm_gi): lane(n,q) holds
// row ROFF(g,s)+n, k = 32kt + 8q + i.  fp32 -> f16 RN (same as fma_mix path).
#define LOADA_ALL(WPTR)                                                        \
  _Pragma("unroll") for (int g = 0; g < 3; ++g)                                \
  _Pragma("unroll") for (int s = 0; s < 2; ++s)                                \
  _Pragma("unroll") for (int kt = 0; kt < 8; ++kt) {                           \
    const float* ap = (WPTR) + (size_t)(256 * g + 32 * w + 16 * s + n) * HDIM  \
                      + 32 * kt + 8 * q;                                       \
    const float4 a0 = *(const float4*)ap;                                      \
    const float4 a1 = *(const float4*)(ap + 4);                                \
    f16x8 tf;                                                                  \
    tf[0] = (_Float16)a0.x; tf[1] = (_Float16)a0.y;                            \
    tf[2] = (_Float16)a0.z; tf[3] = (_Float16)a0.w;                            \
    tf[4] = (_Float16)a1.x; tf[5] = (_Float16)a1.y;                            \
    tf[6] = (_Float16)a1.z; tf[7] = (_Float16)a1.w;                            \
    CAST_A(A[g * 2 + s][kt], tf);                                              \
  }

// One recurrent matvec step: D[768,16] = Whh * (h_hi + h_lo), bias in C.
// kt=0 seeds acc from biasC (no per-step VALU acc init -> no SrcC hazard);
// dependent same-acc MFMAs are 6 apart; s_nop x2 fences MFMA->VALU acc reads.
#define MATCORE(PB)                                                            \
  _Pragma("unroll") for (int kt = 0; kt < 8; ++kt) {                           \
    bh[kt] = *(const f16x8*)&sm.h[PB][0][n][kt * 32 + 8 * q];                  \
    bl[kt] = *(const f16x8*)&sm.h[PB][1][n][kt * 32 + 8 * q];                  \
  }                                                                            \
  _Pragma("unroll") for (int m = 0; m < 6; ++m)                                \
    asm("v_mfma_f32_16x16x32_f16 %0, %1, %2, %3"                               \
        : "=&v"(ac[m]) : "a"(A[m][0]), "v"(bh[0]), "v"(biasC[m]));             \
  _Pragma("unroll") for (int kt = 1; kt < 8; ++kt)                             \
  _Pragma("unroll") for (int m = 0; m < 6; ++m)                                \
    asm("v_mfma_f32_16x16x32_f16 %0, %1, %2, %0"                               \
        : "+v"(ac[m]) : "a"(A[m][kt]), "v"(bh[kt]));                           \
  _Pragma("unroll") for (int kt = 0; kt < 8; ++kt)                             \
  _Pragma("unroll") for (int m = 0; m < 6; ++m)                                \
    asm("v_mfma_f32_16x16x32_f16 %0, %1, %2, %0"                               \
        : "+v"(ac[m]) : "a"(A[m][kt]), "v"(bl[kt]));                           \
  asm volatile("s_nop 7\n\ts_nop 7"                                            \
               : "+v"(ac[0]), "+v"(ac[1]), "+v"(ac[2]),                        \
                 "+v"(ac[3]), "+v"(ac[4]), "+v"(ac[5]));

// Gate math on the D layout (m = 4q+r rows, col n); writes next h buffer.
#define GATES_STORE(PB, GIR, GIZ, GIN, ...)                                    \
  _Pragma("unroll") for (int s = 0; s < 2; ++s) {                              \
    f16x4 vh, vl;                                                              \
    _Pragma("unroll") for (int r = 0; r < 4; ++r) {                            \
      const int m0 = s, m1 = 2 + s, m2 = 4 + s;                                \
      const float rr = sigm((GIR) + ac[m0][r]);                                \
      const float zz = sigm((GIZ) + ac[m1][r]);                                \
      const float nn = tanh_(fmaf(rr, ac[m2][r], (GIN)));                      \
      const float hv = fmaf(zz, hold[s][r] - nn, nn);                          \
      hold[s][r] = hv;                                                         \
      const _Float16 hhi = (_Float16)hv;                                       \
      vh[r] = hhi;                                                             \
      vl[r] = (_Float16)(hv - (float)hhi);                                     \
    }                                                                          \
    const int js = 32 * w + 16 * s + 4 * q;                                    \
    *(f16x4*)&sm.h[(PB) ^ 1][0][n][js] = vh;                                   \
    *(f16x4*)&sm.h[(PB) ^ 1][1][n][js] = vl;                                   \
    __VA_ARGS__                                                                \
  }

// lgkmcnt-only barrier: LDS h handoff ordered, but global stores (ys) and the
// gi prefetch are NOT drained across steps (unlike __syncthreads' vmcnt(0)).
#define BAR asm volatile("s_waitcnt lgkmcnt(0)\n\ts_barrier" ::: "memory")

// =================== Kernel 1: encoder GRU layer 0 (16 batch/block) ==========
__global__ __launch_bounds__(512) void gru_l0(
    const float* __restrict__ x, const float* __restrict__ Wih0,
    const float* __restrict__ Whh0, const float* __restrict__ bih0,
    const float* __restrict__ bhh0, __half* __restrict__ ys) {
  __shared__ RecSmem sm;
  const int tid = threadIdx.x;
  const int w = tid >> 6, lane = tid & 63, n = lane & 15, q = lane >> 4;
  const int b0 = blockIdx.x * NB;
  DECL_MM

  for (int e = tid; e < NB * LSEQ; e += 512) {
    const int bb = e >> 9, tt = e & (LSEQ - 1);
    sm.xt[tt][bb] = x[(size_t)(b0 + bb) * LSEQ + tt];
  }
  {
    float* hz = (float*)&sm.h[0][0][0][0];
    for (int e = tid; e < 4224; e += 512) hz[e] = 0.f;
  }
  LOADA_ALL(Whh0);
  f32x4 wih_v[6], bihn_v[2];
#pragma unroll
  for (int g = 0; g < 3; ++g)
#pragma unroll
    for (int s = 0; s < 2; ++s) {
      const int off = ROFF(g, s);
      wih_v[g * 2 + s] = *(const f32x4*)(Wih0 + off);
      const f32x4 b4 = *(const f32x4*)(bhh0 + off);
      if (g < 2) biasC[g * 2 + s] = b4 + *(const f32x4*)(bih0 + off);
      else { biasC[g * 2 + s] = b4; bihn_v[s] = *(const f32x4*)(bih0 + off); }
    }
#pragma unroll
  for (int s = 0; s < 2; ++s)
#pragma unroll
    for (int r = 0; r < 4; ++r) hold[s][r] = 0.f;
  __syncthreads();

  int pb = 0;
#pragma unroll 1
  for (int t = 0; t < LSEQ; ++t) {
    MATCORE(pb);
    const float xt = sm.xt[t][n];
    GATES_STORE(pb, xt * wih_v[m0][r], xt * wih_v[m1][r],
                fmaf(xt, wih_v[m2][r], bihn_v[s][r]),
                *(f16x4*)(ys + ((size_t)(b0 + n) * LSEQ + t) * HDIM + js) = vh;);
    pb ^= 1;
    BAR;
  }
}

// ============ Kernel 2: GI1 = ys0 @ W_ih1^T + b_ih1 (unchanged, proven) ======
__global__ __launch_bounds__(256) void gemm_gi(
    const float* __restrict__ Wih1, const float* __restrict__ bih1,
    const __half* __restrict__ ys, __half* __restrict__ gi) {
  const int lane = threadIdx.x & 63;
  const int wv = threadIdx.x >> 6;
  const size_t bt0 = (size_t)blockIdx.x << 4;
  const int n = lane & 15, q = lane >> 4;

  f16x8 bfr[8];
  const __half* yrow = ys + (bt0 + n) * HDIM + q * 8;
#pragma unroll
  for (int kk = 0; kk < 8; ++kk) bfr[kk] = *(const f16x8*)(yrow + kk * 32);

#pragma unroll 1
  for (int mt = 0; mt < 12; ++mt) {
    const int j0 = (wv * 12 + mt) << 4;
    const float* arow = Wih1 + (size_t)(j0 + n) * HDIM + q * 8;
    f32x4 acc = {0.f, 0.f, 0.f, 0.f};
#pragma unroll
    for (int kk = 0; kk < 8; ++kk) {
      const float4 a0 = *(const float4*)(arow + kk * 32);
      const float4 a1 = *(const float4*)(arow + kk * 32 + 4);
      f16x8 af;
      af[0] = (_Float16)a0.x; af[1] = (_Float16)a0.y;
      af[2] = (_Float16)a0.z; af[3] = (_Float16)a0.w;
      af[4] = (_Float16)a1.x; af[5] = (_Float16)a1.y;
      af[6] = (_Float16)a1.z; af[7] = (_Float16)a1.w;
      acc = __builtin_amdgcn_mfma_f32_16x16x32_f16(af, bfr[kk], acc, 0, 0, 0);
    }
    const int jr = j0 + (q << 2);
    __half o4[4];
#pragma unroll
    for (int r2 = 0; r2 < 4; ++r2) o4[r2] = __float2half(acc[r2] + bih1[jr + r2]);
    *(uint2*)(gi + (bt0 + n) * 768 + jr) = *(uint2*)o4;
  }
}

// ====== Kernel 3: encoder GRU layer 1 (uses gi) + autoregressive decoder =====
#define LOADGI(PF, T)                                                          \
  {                                                                            \
    const __half* gp = gi + ((size_t)(b0 + n) * LSEQ + (T)) * 768              \
                       + 32 * w + 4 * q;                                       \
    PF[0] = *(const uint2*)(gp);                                               \
    PF[1] = *(const uint2*)(gp + 16);                                          \
    PF[2] = *(const uint2*)(gp + 256);                                         \
    PF[3] = *(const uint2*)(gp + 272);                                         \
    PF[4] = *(const uint2*)(gp + 512);                                         \
    PF[5] = *(const uint2*)(gp + 528);                                         \
  }

#define STEP3(PF)                                                              \
  {                                                                            \
    MATCORE(pb);                                                               \
    float gif[6][4];                                                           \
    _Pragma("unroll") for (int m = 0; m < 6; ++m) {                            \
      const __half2* hp = (const __half2*)&PF[m];                              \
      const float2 f01 = __half22float2(hp[0]);                                \
      const float2 f23 = __half22float2(hp[1]);                                \
      gif[m][0] = f01.x; gif[m][1] = f01.y;                                    \
      gif[m][2] = f23.x; gif[m][3] = f23.y;                                    \
    }                                                                          \
    GATES_STORE(pb, gif[m0][r], gif[m1][r], gif[m2][r], ;);                    \
    pb ^= 1;                                                                   \
    BAR;                                                                       \
  }

__global__ __launch_bounds__(512) void gru_l1dec(
    const float* __restrict__ Whh1, const float* __restrict__ bhh1,
    const float* __restrict__ Wdih, const float* __restrict__ Wdhh,
    const float* __restrict__ bdih, const float* __restrict__ bdhh,
    const float* __restrict__ Wo, const float* __restrict__ bo,
    const __half* __restrict__ gi, float* __restrict__ outp) {
  __shared__ RecSmem sm;
  const int tid = threadIdx.x;
  const int w = tid >> 6, lane = tid & 63, n = lane & 15, q = lane >> 4;
  const int b0 = blockIdx.x * NB;
  DECL_MM

  {
    float* hz = (float*)&sm.h[0][0][0][0];
    for (int e = tid; e < 4224; e += 512) hz[e] = 0.f;
  }
  LOADA_ALL(Whh1);
#pragma unroll
  for (int g = 0; g < 3; ++g)
#pragma unroll
    for (int s = 0; s < 2; ++s)
      biasC[g * 2 + s] = *(const f32x4*)(bhh1 + ROFF(g, s));
#pragma unroll
  for (int s = 0; s < 2; ++s)
#pragma unroll
    for (int r = 0; r < 4; ++r) hold[s][r] = 0.f;
  __syncthreads();

  // ---- phase 3: layer-1 recurrence; gi prefetched one step ahead ----
  uint2 pfA[6], pfB[6];
  LOADGI(pfA, 0);
  int pb = 0;
#pragma unroll 1
  for (int t = 0; t < LSEQ; t += 2) {
    LOADGI(pfB, t + 1);
    STEP3(pfA);
    LOADGI(pfA, (t + 2 < LSEQ) ? (t + 2) : (LSEQ - 1));  // clamp: harmless reload
    STEP3(pfB);
  }

  // ---- phase 4: autoregressive decoder (96 steps) ----
  LOADA_ALL(Wdhh);
  f32x4 wdih_v[6], bdihn_v[2], wo_v[2];
#pragma unroll
  for (int g = 0; g < 3; ++g)
#pragma unroll
    for (int s = 0; s < 2; ++s) {
      const int off = ROFF(g, s);
      wdih_v[g * 2 + s] = *(const f32x4*)(Wdih + off);
      const f32x4 b4 = *(const f32x4*)(bdhh + off);
      if (g < 2) biasC[g * 2 + s] = b4 + *(const f32x4*)(bdih + off);
      else { biasC[g * 2 + s] = b4; bdihn_v[s] = *(const f32x4*)(bdih + off); }
    }
#pragma unroll
  for (int s = 0; s < 2; ++s)
    wo_v[s] = *(const f32x4*)(Wo + 32 * w + 16 * s + 4 * q);
  const float bov = bo[0];
  if (tid < NB) sm.inp[tid] = 0.f;
  BAR;

#pragma unroll 1
  for (int t = 0; t < PRED; ++t) {
    const float it = sm.inp[n];
    MATCORE(pb);
    float c = 0.f;
    GATES_STORE(pb, it * wdih_v[m0][r], it * wdih_v[m1][r],
                fmaf(it, wdih_v[m2][r], bdihn_v[s][r]),
                c += wo_v[s][0] * hold[s][0] + wo_v[s][1] * hold[s][1] +
                     wo_v[s][2] * hold[s][2] + wo_v[s][3] * hold[s][3];);
    c += __shfl_xor(c, 16);   // sum the 4 q-groups holding col n
    c += __shfl_xor(c, 32);
    if (lane < 16) sm.red[w][lane] = c;
    pb ^= 1;
    BAR;
    if (tid < NB) {
      float ov = bov;
#pragma unroll
      for (int ww = 0; ww < 8; ++ww) ov += sm.red[ww][tid];
      outp[(size_t)(b0 + tid) * PRED + t] = ov;
      sm.inp[tid] = ov;
    }
    BAR;
  }
}

extern "C" void kernel_launch(void* const* d_in, const int* in_sizes, int n_in,
                              void* d_out, int out_size, void* d_ws, size_t ws_size,
                              hipStream_t stream) {
  const float* x    = (const float*)d_in[0];
  const float* Wih0 = (const float*)d_in[1];
  const float* Whh0 = (const float*)d_in[2];
  const float* bih0 = (const float*)d_in[3];
  const float* bhh0 = (const float*)d_in[4];
  const float* Wih1 = (const float*)d_in[5];
  const float* Whh1 = (const float*)d_in[6];
  const float* bih1 = (const float*)d_in[7];
  const float* bhh1 = (const float*)d_in[8];
  const float* Wdih = (const float*)d_in[9];
  const float* Wdhh = (const float*)d_in[10];
  const float* bdih = (const float*)d_in[11];
  const float* bdhh = (const float*)d_in[12];
  const float* Wo   = (const float*)d_in[13];
  const float* bo   = (const float*)d_in[14];

  // ws layout: ys0 (f16, 64 MiB) | GI1 (f16, 192 MiB)
  __half* ys = (__half*)d_ws;
  __half* gi = ys + (size_t)256 * 512 * 256;

  gru_l0<<<NBLK, 512, 0, stream>>>(x, Wih0, Whh0, bih0, bhh0, ys);
  gemm_gi<<<(256 * 512) / 16, 256, 0, stream>>>(Wih1, bih1, ys, gi);
  gru_l1dec<<<NBLK, 512, 0, stream>>>(Whh1, bhh1, Wdih, Wdhh, bdih, bdhh,
                                      Wo, bo, gi, (float*)d_out);
}